// Round 4
// baseline (299.027 us; speedup 1.0000x reference)
//
#include <hip/hip_runtime.h>
#include <float.h>

#define HW    4096      // H*W
#define NC    64        // channels / latent dim
#define NK    1024      // codebook entries
#define NB    32        // batch
#define NPIX  (NB*HW)   // 131072 pixels
#define TOTAL (NPIX*NC) // 8388608 output elements of z_q
#define PPB   128       // pixels per block (16 per wave, 8 waves)

// R4 numerics: codebook held as SINGLE-level fp16 (11-bit mantissa), z split
// fp16 hi/lo. score_err <= 2*||e_lo||*||z|| (Cauchy-Schwarz) per score, where
// e_lo = e - fp32(fp16(e)). Flag margin per pixel:
//   4 * E_max * ||z_p|| + SLACK,  E_max = max_k ||e_lo,k|| (exact, from prep)
// SLACK covers fp32-accum rounding, z-split residual, and worst-case fp16
// denormal flushing in the MFMA. gap2 < margin -> exact fp64 rescan.
#define SLACK 0.03f

typedef __attribute__((ext_vector_type(8))) _Float16 f16x8;  // 8 fp16 (4 VGPRs)
typedef __attribute__((ext_vector_type(4))) float   floatx4; // MFMA acc

__device__ __forceinline__ unsigned short f2h_bits(float f) {  // fp32->fp16 RNE
    _Float16 h = (_Float16)f;
    union { _Float16 h; unsigned short u; } c; c.h = h;
    return c.u;
}

// Prep: blocks 0..63 element-parallel fp16 convert, coalesced 16B-in/8B-out.
// Blocks 64..67: fp64-accurate cnorm + per-block max ||e_lo||^2.
__global__ void vq_prep_kernel(const float* __restrict__ cb,
                               float* __restrict__ cnorm,
                               unsigned short* __restrict__ cb_h,
                               float* __restrict__ e2max,
                               float* __restrict__ loss_out) {
    const int b = blockIdx.x;
    if (b < 64) {
        const int i = b * 256 + threadIdx.x;     // float4 index, 16384 total
        if (i == 0) loss_out[0] = 0.0f;
        float4 v = ((const float4*)cb)[i];
        unsigned short h0 = f2h_bits(v.x), h1 = f2h_bits(v.y),
                       h2 = f2h_bits(v.z), h3 = f2h_bits(v.w);
        uint2 ph = make_uint2((unsigned)h0 | ((unsigned)h1 << 16),
                              (unsigned)h2 | ((unsigned)h3 << 16));
        ((uint2*)cb_h)[i] = ph;                  // coalesced 8B stores
    } else {
        __shared__ float wmax[4];
        const int k = (b - 64) * 256 + threadIdx.x;  // 0..1023
        const float4* r4 = (const float4*)(cb + (size_t)k * NC);
        double s = 0.0;
        float  e2 = 0.0f;
        #pragma unroll
        for (int j = 0; j < 16; ++j) {
            float4 v = r4[j];
            s = fma((double)v.x, (double)v.x, s);
            s = fma((double)v.y, (double)v.y, s);
            s = fma((double)v.z, (double)v.z, s);
            s = fma((double)v.w, (double)v.w, s);
            float l0 = v.x - (float)(_Float16)v.x;
            float l1 = v.y - (float)(_Float16)v.y;
            float l2 = v.z - (float)(_Float16)v.z;
            float l3 = v.w - (float)(_Float16)v.w;
            e2 = fmaf(l0, l0, e2); e2 = fmaf(l1, l1, e2);
            e2 = fmaf(l2, l2, e2); e2 = fmaf(l3, l3, e2);
        }
        cnorm[k] = (float)s;
        #pragma unroll
        for (int off = 32; off > 0; off >>= 1)
            e2 = fmaxf(e2, __shfl_down(e2, off));
        if ((threadIdx.x & 63) == 0) wmax[threadIdx.x >> 6] = e2;
        __syncthreads();
        if (threadIdx.x == 0)
            e2max[b - 64] = fmaxf(fmaxf(wmax[0], wmax[1]),
                                  fmaxf(wmax[2], wmax[3]));
    }
}

// Main, R4: fp16 single-level A. Per 16-code tile: 2 ds_read_b128 (A was 4)
// + 4 chained MFMA (was 6) seeded with cn4 (kills the a0+a1 adds). Keeps the
// R3 wave layout (8 waves x 16 px -> 8 waves/SIMD) and R2/R3 async staging
// with both-sides-consistent swizzle. Rationale: R1-R3 falsified every
// scheduling theory (barriers, staging, TLP) -- duration is pinned by total
// pipe WORK; this round removes 33% of MFMA and 50% of LDS-read work.
__global__ __launch_bounds__(512, 8) void vq_mfma_kernel(
        const float* __restrict__ z,
        const float* __restrict__ cb,
        const unsigned short* __restrict__ cb_h,
        const float* __restrict__ cnorm,
        const float* __restrict__ e2max,
        float* __restrict__ zq,
        float* __restrict__ loss_out) {
    // [buf(2)][tile_in_interval(4)*128 + slot(128)] uint4 units, 16 KB.
    // Within one tile: slot = row(16)*8 + chunk(8), chunk^(row&7) swizzle.
    __shared__ alignas(16) uint4  abuf[2][512];
    __shared__ alignas(16) float  cn_lds[NK];   // 4 KB; rescan scratch aliases
    __shared__ int   finidx[PPB];
    __shared__ int   flags[PPB];
    __shared__ float redf[8];

    const int tid = threadIdx.x;
    const int g0  = blockIdx.x * PPB;
    const int bb  = g0 >> 12;
    const int pp0 = g0 & 4095;
    const float* zbase = z  + (size_t)bb * (NC * HW) + pp0;
    float*      zqbase = zq + (size_t)bb * (NC * HW) + pp0;

    // ---- stage cnorm -> LDS (512 threads x float2) ----
    ((float2*)cn_lds)[tid] = ((const float2*)cnorm)[tid];

    const int lane = tid & 63;
    const int w    = tid >> 6;        // wave 0..7 -> pixels w*16..w*16+15
    const int q    = lane >> 4;
    const int pcol = lane & 15;

    // ---- pre-swizzled global source for linear global_load_lds dest ----
    // Thread tid fills LDS slot tid (linear, as global_load_lds requires).
    // Slot (tt,row,chunk) holds global chunk^(row&7) -> XOR on the SOURCE.
    {
    }
    const int  stt   = tid >> 7;
    const int  srow  = (tid >> 3) & 15;
    const int  schk  = tid & 7;
    const char* gsrc = (const char*)cb_h + stt * 2048 + srow * 128
                       + ((schk ^ (srow & 7)) * 16);

    // one 4-tile interval of staging = 8 KB = 512 threads x 16B
    auto stage_iv = [&](int iv, int buf) {
        __builtin_amdgcn_global_load_lds(
            (const __attribute__((address_space(1))) void*)
                (gsrc + (size_t)iv * 8192),
            (__attribute__((address_space(3))) void*)&abuf[buf][tid],
            16, 0, 0);
    };

    stage_iv(0, 0);   // interval 0 in flight; z-loads below cover its latency

    // ---- B fragments straight from global: 16 strided floats per lane ----
    // B[k][n]: n = this wave's pixel (w*16+pcol), k = ks*32 + q*8 + t
    float zraw[2][8];
    #pragma unroll
    for (int ks = 0; ks < 2; ++ks)
        #pragma unroll
        for (int t = 0; t < 8; ++t)
            zraw[ks][t] = zbase[(size_t)(ks * 32 + q * 8 + t) * HW
                                + (w * 16 + pcol)];

    // per-pixel ||z||^2: this lane's 16 channels, then reduce across quads
    float nz2 = 0.0f;
    #pragma unroll
    for (int ks = 0; ks < 2; ++ks)
        #pragma unroll
        for (int t = 0; t < 8; ++t)
            nz2 = fmaf(zraw[ks][t], zraw[ks][t], nz2);
    nz2 += __shfl_xor(nz2, 16);
    nz2 += __shfl_xor(nz2, 32);

    f16x8 Bh[2], Bl[2];
    #pragma unroll
    for (int ks = 0; ks < 2; ++ks)
        #pragma unroll
        for (int t = 0; t < 8; ++t) {
            float v = -2.0f * zraw[ks][t];
            _Float16 vh = (_Float16)v;
            _Float16 vl = (_Float16)(v - (float)vh);
            Bh[ks][t] = vh;
            Bl[ks][t] = vl;
        }

    // rigorous per-pixel flag margin (see header comment)
    const float e2m = fmaxf(fmaxf(e2max[0], e2max[1]),
                            fmaxf(e2max[2], e2max[3]));
    const float margin = 4.0f * sqrtf(e2m) * sqrtf(nz2) + SLACK;

    // per-lane fixed read offsets (uint4 units within one tile's 128 slots)
    const int ridx0 = pcol * 8 + (q ^ (pcol & 7));        // chunk q  (k 0..31)
    const int ridx1 = pcol * 8 + ((4 + q) ^ (pcol & 7));  // chunk 4+q (k 32..63)

    __syncthreads();   // interval-0 staging drained (compiler vmcnt(0)) + cn_lds

    float B1 = FLT_MAX, B2 = FLT_MAX;
    int   I1 = 0;

    // ---- sweep 64 code tiles as 16 intervals of 4, double-buffered ----
    for (int iv = 0; iv < 16; ++iv) {
        if (iv < 15) stage_iv(iv + 1, (iv + 1) & 1);
        #pragma unroll
        for (int tt = 0; tt < 4; ++tt) {
            const f16x8* A = (const f16x8*)&abuf[iv & 1][tt * 128];
            f16x8 ah0 = A[ridx0];
            f16x8 ah1 = A[ridx1];
            const int tile = iv * 4 + tt;
            const floatx4 cn4 = *(const floatx4*)&cn_lds[tile * 16 + q * 4];
            const int kb = tile * 16 + q * 4;
            // score = cn + e_h.(-2z)_h + e_h.(-2z)_l  (single chained acc)
            floatx4 a = __builtin_amdgcn_mfma_f32_16x16x32_f16(ah0, Bh[0], cn4, 0, 0, 0);
            a = __builtin_amdgcn_mfma_f32_16x16x32_f16(ah0, Bl[0], a, 0, 0, 0);
            a = __builtin_amdgcn_mfma_f32_16x16x32_f16(ah1, Bh[1], a, 0, 0, 0);
            a = __builtin_amdgcn_mfma_f32_16x16x32_f16(ah1, Bl[1], a, 0, 0, 0);

            // C/D layout: code row = q*4+reg, pixel col = lane&15 (verified;
            // dtype-independent on gfx950)
            #pragma unroll
            for (int i = 0; i < 4; ++i) {
                float s = a[i];
                bool lt = s < B1;                    // strict: first min wins
                I1 = lt ? (kb + i) : I1;
                B2 = __builtin_amdgcn_fmed3f(s, B1, B2);
                B1 = fminf(s, B1);
            }
        }
        __syncthreads();
    }

    // ---- merge top-2 across the 4 lanes sharing each pixel (xor 16,32) ----
    {
        float b1 = B1, b2 = B2;
        int i1 = I1;
        #pragma unroll
        for (int d = 16; d <= 32; d <<= 1) {
            float ob1 = __shfl_xor(b1, d);
            float ob2 = __shfl_xor(b2, d);
            int   oi1 = __shfl_xor(i1, d);
            // second-smallest of {b1,b2,ob1,ob2}; equal b1s -> gap 0 -> rescan
            float nb2 = fminf(fmaxf(b1, ob1), fminf(b2, ob2));
            bool lt = (ob1 < b1) || (ob1 == b1 && oi1 < i1);
            b1 = lt ? ob1 : b1;
            i1 = lt ? oi1 : i1;
            b2 = nb2;
        }
        if (q == 0) {
            const int px = w * 16 + pcol;
            finidx[px] = i1;
            flags[px]  = (b2 - b1 < margin) ? 1 : 0;
        }
    }
    int myflag = 0;
    __syncthreads();
    if (tid < PPB) myflag = flags[tid];
    const int nflag = __syncthreads_count(myflag);

    // ---- rare cooperative exact fp64 rescan ----
    // red_s aliases cn_lds (512 doubles = 4 KB); red_i aliases abuf (free).
    if (nflag > 0) {
        double* red_s = reinterpret_cast<double*>(cn_lds);
        int*    red_i = reinterpret_cast<int*>(&abuf[0][0]);
        for (int p = 0; p < PPB; ++p) {
            if (flags[p]) {
                const float* zp = zbase + p;
                double bd = 1.0e300; int bi = 0;
                #pragma unroll 1
                for (int r = 0; r < 2; ++r) {
                    const int k = tid * 2 + r;
                    const float* rowp = cb + (size_t)k * NC;
                    double s = 0.0;
                    for (int c = 0; c < NC; ++c) {
                        double t = (double)zp[(size_t)c * HW] - (double)rowp[c];
                        s = fma(t, t, s);
                    }
                    if (s < bd) { bd = s; bi = k; }  // k increasing: first min
                }
                red_s[tid] = bd; red_i[tid] = bi;
                __syncthreads();
                if (tid < 64) {
                    double m = red_s[tid]; int mi = red_i[tid];
                    #pragma unroll
                    for (int t = 1; t < 8; ++t) {
                        double om = red_s[tid + 64 * t];
                        int    oi = red_i[tid + 64 * t];
                        if (om < m || (om == m && oi < mi)) { m = om; mi = oi; }
                    }
                    #pragma unroll
                    for (int off = 32; off > 0; off >>= 1) {
                        double om = __shfl_down(m, off);
                        int    oi = __shfl_down(mi, off);
                        if (om < m || (om == m && oi < mi)) { m = om; mi = oi; }
                    }
                    if (tid == 0) finidx[p] = mi;
                }
                __syncthreads();
            }
        }
        __syncthreads();
    }

    // ---- epilogue: gather exact fp32 code row -> z_q, loss SSE ----
    // 4 threads per pixel, 16 channels each.
    {
        const int p  = tid & (PPB - 1);
        const int qq = tid >> 7;             // 0..3
        const int fi = finidx[p];
        const float4* crow4 = (const float4*)(cb + (size_t)fi * NC) + qq * 4;
        float sse = 0.f;
        #pragma unroll
        for (int j = 0; j < 4; ++j) {
            const float4 qv = crow4[j];
            const size_t c0 = (size_t)(qq * 16 + 4 * j) * HW + p;
            const float z0 = zbase[c0];
            const float z1 = zbase[c0 + HW];
            const float z2 = zbase[c0 + 2 * (size_t)HW];
            const float z3 = zbase[c0 + 3 * (size_t)HW];
            zqbase[c0]                  = qv.x;   // coalesced across threads
            zqbase[c0 + HW]             = qv.y;
            zqbase[c0 + 2 * (size_t)HW] = qv.z;
            zqbase[c0 + 3 * (size_t)HW] = qv.w;
            float t0 = qv.x - z0, t1 = qv.y - z1, t2 = qv.z - z2, t3 = qv.w - z3;
            sse = fmaf(t0, t0, sse);
            sse = fmaf(t1, t1, sse);
            sse = fmaf(t2, t2, sse);
            sse = fmaf(t3, t3, sse);
        }
        #pragma unroll
        for (int off = 32; off > 0; off >>= 1) sse += __shfl_down(sse, off);
        if ((tid & 63) == 0) redf[tid >> 6] = sse;
        __syncthreads();
        if (tid == 0) {
            float tot = 0.f;
            #pragma unroll
            for (int r = 0; r < 8; ++r) tot += redf[r];
            atomicAdd(loss_out, tot * (1.25f / (float)TOTAL));
        }
    }
}

extern "C" void kernel_launch(void* const* d_in, const int* in_sizes, int n_in,
                              void* d_out, int out_size, void* d_ws, size_t ws_size,
                              hipStream_t stream) {
    const float* z  = (const float*)d_in[0];   // [32, 64, 64, 64] fp32
    const float* cb = (const float*)d_in[1];   // [1024, 64] fp32
    float* out      = (float*)d_out;           // z_q ++ loss
    float* zqp      = out;
    float* loss     = out + TOTAL;

    // ws: cnorm fp32[1024] | e2max fp32[4] | pad | cb_h fp16[1024*64]
    float* cnorm          = (float*)d_ws;
    float* e2max          = (float*)((char*)d_ws + 4096);
    unsigned short* cb_h  = (unsigned short*)((char*)d_ws + 8192);

    vq_prep_kernel<<<68, 256, 0, stream>>>(cb, cnorm, cb_h, e2max, loss);
    vq_mfma_kernel<<<NPIX / PPB, 512, 0, stream>>>(z, cb, cb_h, cnorm, e2max,
                                                   zqp, loss);
}

// Round 6
// 208.521 us; speedup vs baseline: 1.4340x; 1.4340x over previous
//
#include <hip/hip_runtime.h>
#include <float.h>

#define HW    4096      // H*W
#define NC    64        // channels / latent dim
#define NK    1024      // codebook entries
#define NB    32        // batch
#define NPIX  (NB*HW)   // 131072 pixels
#define TOTAL (NPIX*NC) // 8388608 output elements of z_q
#define PPB   128       // pixels per block (16 per wave, 8 waves)

// bf16 hi/lo split score error bound ~1.4e-3 worst case (+ ~1e-4 fp32 cnorm)
// vs MARGIN 8e-3: >4x safety (margin validated rounds 4-9 + R0-R3, absmax 0).
// gap2 < MARGIN (incl. any exact fp32 tie) -> cooperative exact fp64 rescan
// (~0.13% of pixels).
#define MARGIN 8e-3f

typedef __attribute__((ext_vector_type(8))) short short8;   // 8 bf16 (4 VGPRs)
typedef __attribute__((ext_vector_type(4))) float floatx4;  // MFMA acc

__device__ __forceinline__ unsigned short f2bf(float f) {   // fp32 -> bf16 RNE
    unsigned u = __float_as_uint(f);
    u += 0x7FFFu + ((u >> 16) & 1u);
    return (unsigned short)(u >> 16);
}
__device__ __forceinline__ float bf2f(unsigned short h) {
    return __uint_as_float(((unsigned)h) << 16);
}

// R6: SINGLE fused kernel (R5 with the staging-stride bug fixed: one interval
// = 64 codes = 1024 float4, source must advance iv*1024, not iv*256 -- R5's
// intervals 1..15 restaged wrong rows -> absmax 6.28).
// Rationale (R5): R0-R3 pinned the sweep at ~104-112 us, but the BENCH metric
// ran 62-71 us higher every round -- prep kernel + inter-kernel gap + second
// launch is a fixed tax ~60% of the main kernel. Fuse it away:
//   - cnorm: per-block (512 thr x 2 rows x 64 fp32 fma, 4-way split
//     accumulators; error ~1e-4 << margin budget). cb is L2/L3-resident.
//   - codebook bf16 hi/lo: converted on-the-fly during staging (fp32 load ->
//     f2bf in reg -> ds_write_b128 into the SWIZZLED slot). Reg-staging has
//     no linear-dest constraint, so the swizzle goes on the write address;
//     read side byte-identical to the verified R0/R3 layout.
//   - sweep / min-track / rescan / epilogue: identical to R3 (validated
//     MARGIN, 0.13% rescan rate).
// Block = 512 threads / 8 waves / 128 pixels (16 px per wave).
__global__ __launch_bounds__(512, 8) void vq_mfma_kernel(
        const float* __restrict__ z,
        const float* __restrict__ cb,
        float* __restrict__ zq,
        float* __restrict__ loss_out) {
    // [buf(2)][tile(4)*256 + part(2)*128 + row(16)*8 + chunk(8)] uint4 = 32 KB
    // Within one tile: slot chunk field cf at row r holds global chunk
    // cf^(r&7) (R0 swizzle; read-side verified conflict-free).
    __shared__ alignas(16) uint4  abuf[2][1024];
    __shared__ alignas(16) float  cn_lds[NK];   // 4 KB; rescan scratch aliases
    __shared__ int   finidx[PPB];
    __shared__ int   flags[PPB];
    __shared__ float redf[8];

    const int tid = threadIdx.x;
    const int g0  = blockIdx.x * PPB;
    const int bb  = g0 >> 12;
    const int pp0 = g0 & 4095;
    const float* zbase = z  + (size_t)bb * (NC * HW) + pp0;
    float*      zqbase = zq + (size_t)bb * (NC * HW) + pp0;

    const int lane = tid & 63;
    const int w    = tid >> 6;        // wave 0..7 -> pixels w*16..w*16+15
    const int q    = lane >> 4;
    const int pcol = lane & 15;

    // ---- per-block cnorm: thread computes rows 2*tid, 2*tid+1 ----
    // 4-way split accumulation: error ~1e-4, inside margin budget.
    #pragma unroll
    for (int r = 0; r < 2; ++r) {
        const int k = tid * 2 + r;
        const float4* r4 = (const float4*)(cb + (size_t)k * NC);
        float4 acc = {0.f, 0.f, 0.f, 0.f};
        #pragma unroll
        for (int j = 0; j < 16; ++j) {
            float4 v = r4[j];
            acc.x = fmaf(v.x, v.x, acc.x);
            acc.y = fmaf(v.y, v.y, acc.y);
            acc.z = fmaf(v.z, v.z, acc.z);
            acc.w = fmaf(v.w, v.w, acc.w);
        }
        cn_lds[k] = (acc.x + acc.y) + (acc.z + acc.w);
    }

    // ---- convert-on-stage: fp32 cb -> bf16 hi/lo -> swizzled LDS ----
    // Per interval (4 tiles, 64 codes = 4096 floats = 1024 float4): thread
    // tid handles code (stt*16+srow) channels schk*8..+7 -> two float4 loads,
    // writes hi uint4 to slot chunk field schk^(srow&7), lo to +128.
    const int stt  = tid >> 7;
    const int srow = (tid >> 3) & 15;
    const int schk = tid & 7;
    const float4* gsrc4 = (const float4*)(cb + ((size_t)stt * 16 + srow) * NC
                                          + schk * 8);
    const int wslot = stt * 256 + srow * 8 + (schk ^ (srow & 7));

    auto stage_iv = [&](int iv, int buf) {
        // interval iv covers codes iv*64 .. iv*64+63 -> +iv*1024 float4
        const float4 v0 = gsrc4[(size_t)iv * 1024];
        const float4 v1 = gsrc4[(size_t)iv * 1024 + 1];
        unsigned short h0 = f2bf(v0.x), h1 = f2bf(v0.y),
                       h2 = f2bf(v0.z), h3 = f2bf(v0.w),
                       h4 = f2bf(v1.x), h5 = f2bf(v1.y),
                       h6 = f2bf(v1.z), h7 = f2bf(v1.w);
        unsigned short l0 = f2bf(v0.x - bf2f(h0)), l1 = f2bf(v0.y - bf2f(h1)),
                       l2 = f2bf(v0.z - bf2f(h2)), l3 = f2bf(v0.w - bf2f(h3)),
                       l4 = f2bf(v1.x - bf2f(h4)), l5 = f2bf(v1.y - bf2f(h5)),
                       l6 = f2bf(v1.z - bf2f(h6)), l7 = f2bf(v1.w - bf2f(h7));
        uint4 ph, pl;
        ph.x = (unsigned)h0 | ((unsigned)h1 << 16);
        ph.y = (unsigned)h2 | ((unsigned)h3 << 16);
        ph.z = (unsigned)h4 | ((unsigned)h5 << 16);
        ph.w = (unsigned)h6 | ((unsigned)h7 << 16);
        pl.x = (unsigned)l0 | ((unsigned)l1 << 16);
        pl.y = (unsigned)l2 | ((unsigned)l3 << 16);
        pl.z = (unsigned)l4 | ((unsigned)l5 << 16);
        pl.w = (unsigned)l6 | ((unsigned)l7 << 16);
        abuf[buf][wslot]       = ph;   // hi part
        abuf[buf][wslot + 128] = pl;   // lo part (within-tile +128)
    };

    stage_iv(0, 0);   // interval 0; overlaps with z loads below

    // ---- B fragments straight from global: 16 strided floats per lane ----
    // B[k][n]: n = this wave's pixel (w*16+pcol), k = ks*32 + q*8 + t
    float zraw[2][8];
    #pragma unroll
    for (int ks = 0; ks < 2; ++ks)
        #pragma unroll
        for (int t = 0; t < 8; ++t)
            zraw[ks][t] = zbase[(size_t)(ks * 32 + q * 8 + t) * HW
                                + (w * 16 + pcol)];
    short8 Bh[2], Bl[2];
    #pragma unroll
    for (int ks = 0; ks < 2; ++ks)
        #pragma unroll
        for (int t = 0; t < 8; ++t) {
            float v = -2.0f * zraw[ks][t];
            unsigned short h = f2bf(v);
            unsigned short l = f2bf(v - bf2f(h));
            Bh[ks][t] = (short)h;
            Bl[ks][t] = (short)l;
        }

    // per-lane fixed read offsets (uint4 units within one tile's 256 slots)
    const int ridx0 = pcol * 8 + (q ^ (pcol & 7));        // chunk q  (k 0..31)
    const int ridx1 = pcol * 8 + ((4 + q) ^ (pcol & 7));  // chunk 4+q (k 32..63)

    __syncthreads();   // cn_lds + abuf[0] (all reg-staged ds_writes) visible

    float B1 = FLT_MAX, B2 = FLT_MAX;
    int   I1 = 0;

    // ---- sweep 64 code tiles as 16 intervals of 4, double-buffered ----
    // WAR-safe: stage writes buf^1, last read in interval iv-1 whose end
    // barrier precedes these writes.
    for (int iv = 0; iv < 16; ++iv) {
        if (iv < 15) stage_iv(iv + 1, (iv + 1) & 1);
        #pragma unroll
        for (int tt = 0; tt < 4; ++tt) {
            const short8* A = (const short8*)&abuf[iv & 1][tt * 256];
            short8 ah0 = A[ridx0];
            short8 ah1 = A[ridx1];
            short8 al0 = A[128 + ridx0];
            short8 al1 = A[128 + ridx1];
            const int tile = iv * 4 + tt;
            const floatx4 cn4 = *(const floatx4*)&cn_lds[tile * 16 + q * 4];
            const int kb = tile * 16 + q * 4;
            // score = cn + (-2z).e :  e_hi*z_hi + e_hi*z_lo + e_lo*z_hi
            floatx4 a0 = __builtin_amdgcn_mfma_f32_16x16x32_bf16(ah0, Bh[0], cn4, 0, 0, 0);
            floatx4 a1 = {0.f, 0.f, 0.f, 0.f};
            a1 = __builtin_amdgcn_mfma_f32_16x16x32_bf16(ah1, Bh[1], a1, 0, 0, 0);
            a0 = __builtin_amdgcn_mfma_f32_16x16x32_bf16(ah0, Bl[0], a0, 0, 0, 0);
            a1 = __builtin_amdgcn_mfma_f32_16x16x32_bf16(ah1, Bl[1], a1, 0, 0, 0);
            a0 = __builtin_amdgcn_mfma_f32_16x16x32_bf16(al0, Bh[0], a0, 0, 0, 0);
            a1 = __builtin_amdgcn_mfma_f32_16x16x32_bf16(al1, Bh[1], a1, 0, 0, 0);

            // C/D layout: code row = q*4+reg, pixel col = lane&15 (verified)
            #pragma unroll
            for (int i = 0; i < 4; ++i) {
                float s = a0[i] + a1[i];
                bool lt = s < B1;                    // strict: first min wins
                I1 = lt ? (kb + i) : I1;
                B2 = __builtin_amdgcn_fmed3f(s, B1, B2);
                B1 = fminf(s, B1);
            }
        }
        __syncthreads();
    }

    // ---- merge top-2 across the 4 lanes sharing each pixel (xor 16,32) ----
    {
        float b1 = B1, b2 = B2;
        int i1 = I1;
        #pragma unroll
        for (int d = 16; d <= 32; d <<= 1) {
            float ob1 = __shfl_xor(b1, d);
            float ob2 = __shfl_xor(b2, d);
            int   oi1 = __shfl_xor(i1, d);
            // second-smallest of {b1,b2,ob1,ob2}; equal b1s -> gap 0 -> rescan
            float nb2 = fminf(fmaxf(b1, ob1), fminf(b2, ob2));
            bool lt = (ob1 < b1) || (ob1 == b1 && oi1 < i1);
            b1 = lt ? ob1 : b1;
            i1 = lt ? oi1 : i1;
            b2 = nb2;
        }
        if (q == 0) {
            const int px = w * 16 + pcol;
            finidx[px] = i1;
            flags[px]  = (b2 - b1 < MARGIN) ? 1 : 0;
        }
    }
    int myflag = 0;
    __syncthreads();
    if (tid < PPB) myflag = flags[tid];
    const int nflag = __syncthreads_count(myflag);

    // ---- rare cooperative exact fp64 rescan ----
    // red_s aliases cn_lds (512 doubles = 4 KB); red_i aliases abuf (free).
    if (nflag > 0) {
        double* red_s = reinterpret_cast<double*>(cn_lds);
        int*    red_i = reinterpret_cast<int*>(&abuf[0][0]);
        for (int p = 0; p < PPB; ++p) {
            if (flags[p]) {
                const float* zp = zbase + p;
                double bd = 1.0e300; int bi = 0;
                #pragma unroll 1
                for (int r = 0; r < 2; ++r) {
                    const int k = tid * 2 + r;
                    const float* rowp = cb + (size_t)k * NC;
                    double s = 0.0;
                    for (int c = 0; c < NC; ++c) {
                        double t = (double)zp[(size_t)c * HW] - (double)rowp[c];
                        s = fma(t, t, s);
                    }
                    if (s < bd) { bd = s; bi = k; }  // k increasing: first min
                }
                red_s[tid] = bd; red_i[tid] = bi;
                __syncthreads();
                if (tid < 64) {
                    double m = red_s[tid]; int mi = red_i[tid];
                    #pragma unroll
                    for (int t = 1; t < 8; ++t) {
                        double om = red_s[tid + 64 * t];
                        int    oi = red_i[tid + 64 * t];
                        if (om < m || (om == m && oi < mi)) { m = om; mi = oi; }
                    }
                    #pragma unroll
                    for (int off = 32; off > 0; off >>= 1) {
                        double om = __shfl_down(m, off);
                        int    oi = __shfl_down(mi, off);
                        if (om < m || (om == m && oi < mi)) { m = om; mi = oi; }
                    }
                    if (tid == 0) finidx[p] = mi;
                }
                __syncthreads();
            }
        }
        __syncthreads();
    }

    // ---- epilogue: gather exact fp32 code row -> z_q, loss SSE ----
    // 4 threads per pixel, 16 channels each.
    {
        const int p  = tid & (PPB - 1);
        const int qq = tid >> 7;             // 0..3
        const int fi = finidx[p];
        const float4* crow4 = (const float4*)(cb + (size_t)fi * NC) + qq * 4;
        float sse = 0.f;
        #pragma unroll
        for (int j = 0; j < 4; ++j) {
            const float4 qv = crow4[j];
            const size_t c0 = (size_t)(qq * 16 + 4 * j) * HW + p;
            const float z0 = zbase[c0];
            const float z1 = zbase[c0 + HW];
            const float z2 = zbase[c0 + 2 * (size_t)HW];
            const float z3 = zbase[c0 + 3 * (size_t)HW];
            zqbase[c0]                  = qv.x;   // coalesced across threads
            zqbase[c0 + HW]             = qv.y;
            zqbase[c0 + 2 * (size_t)HW] = qv.z;
            zqbase[c0 + 3 * (size_t)HW] = qv.w;
            float t0 = qv.x - z0, t1 = qv.y - z1, t2 = qv.z - z2, t3 = qv.w - z3;
            sse = fmaf(t0, t0, sse);
            sse = fmaf(t1, t1, sse);
            sse = fmaf(t2, t2, sse);
            sse = fmaf(t3, t3, sse);
        }
        #pragma unroll
        for (int off = 32; off > 0; off >>= 1) sse += __shfl_down(sse, off);
        if ((tid & 63) == 0) redf[tid >> 6] = sse;
        __syncthreads();
        if (tid == 0) {
            float tot = 0.f;
            #pragma unroll
            for (int r = 0; r < 8; ++r) tot += redf[r];
            atomicAdd(loss_out, tot * (1.25f / (float)TOTAL));
        }
    }
}

extern "C" void kernel_launch(void* const* d_in, const int* in_sizes, int n_in,
                              void* d_out, int out_size, void* d_ws, size_t ws_size,
                              hipStream_t stream) {
    const float* z  = (const float*)d_in[0];   // [32, 64, 64, 64] fp32
    const float* cb = (const float*)d_in[1];   // [1024, 64] fp32
    float* out      = (float*)d_out;           // z_q ++ loss
    float* zqp      = out;
    float* loss     = out + TOTAL;

    hipMemsetAsync(loss, 0, sizeof(float), stream);   // graph-capture-safe
    vq_mfma_kernel<<<NPIX / PPB, 512, 0, stream>>>(z, cb, zqp, loss);
}

// Round 9
// 174.933 us; speedup vs baseline: 1.7094x; 1.1920x over previous
//
#include <hip/hip_runtime.h>
#include <float.h>

#define HW    4096      // H*W
#define NC    64        // channels / latent dim
#define NK    1024      // codebook entries
#define NB    32        // batch
#define NPIX  (NB*HW)   // 131072 pixels
#define TOTAL (NPIX*NC) // 8388608 output elements of z_q
#define PPB   128       // pixels per block (16 per wave, 8 waves)

// bf16 hi/lo split score error bound ~1.4e-3 worst case; MARGIN 8e-3 gives
// >4x safety (validated rounds 4-9, absmax 0). gap2<MARGIN (incl. any exact
// fp32 tie) -> cooperative exact fp64 full rescan (~0.13%/pixel).
#define MARGIN 8e-3f

typedef __attribute__((ext_vector_type(8))) short short8;   // 8 bf16 (4 VGPRs)
typedef __attribute__((ext_vector_type(4))) float floatx4;  // MFMA acc

__device__ __forceinline__ unsigned short f2bf(float f) {   // fp32 -> bf16 RNE
    unsigned u = __float_as_uint(f);
    u += 0x7FFFu + ((u >> 16) & 1u);
    return (unsigned short)(u >> 16);
}
__device__ __forceinline__ float bf2f(unsigned short h) {
    return __uint_as_float(((unsigned)h) << 16);
}

// Prep: blocks 0..63 element-parallel bf16 hi/lo split, fully coalesced
// 16B-in / 8B-out. Blocks 64..67: fp64-accurate cnorm.
__global__ void vq_prep_kernel(const float* __restrict__ cb,
                               float* __restrict__ cnorm,
                               unsigned short* __restrict__ cb_hi,
                               unsigned short* __restrict__ cb_lo,
                               float* __restrict__ loss_out) {
    const int b = blockIdx.x;
    if (b < 64) {
        const int i = b * 256 + threadIdx.x;     // float4 index, 16384 total
        if (i == 0) loss_out[0] = 0.0f;
        float4 v = ((const float4*)cb)[i];
        unsigned short h0 = f2bf(v.x), h1 = f2bf(v.y),
                       h2 = f2bf(v.z), h3 = f2bf(v.w);
        unsigned short l0 = f2bf(v.x - bf2f(h0)), l1 = f2bf(v.y - bf2f(h1)),
                       l2 = f2bf(v.z - bf2f(h2)), l3 = f2bf(v.w - bf2f(h3));
        uint2 ph = make_uint2((unsigned)h0 | ((unsigned)h1 << 16),
                              (unsigned)h2 | ((unsigned)h3 << 16));
        uint2 pl = make_uint2((unsigned)l0 | ((unsigned)l1 << 16),
                              (unsigned)l2 | ((unsigned)l3 << 16));
        ((uint2*)cb_hi)[i] = ph;                 // coalesced 8B stores
        ((uint2*)cb_lo)[i] = pl;
    } else {
        const int k = (b - 64) * 256 + threadIdx.x;  // 0..1023
        const float4* r4 = (const float4*)(cb + (size_t)k * NC);
        double s = 0.0;
        #pragma unroll
        for (int j = 0; j < 16; ++j) {
            float4 v = r4[j];
            s = fma((double)v.x, (double)v.x, s);
            s = fma((double)v.y, (double)v.y, s);
            s = fma((double)v.z, (double)v.z, s);
            s = fma((double)v.w, (double)v.w, s);
        }
        cnorm[k] = (float)s;
    }
}

// Main (R8 = R3 restored, the best-measured config: main 103.6 us):
// block = 512 threads / 8 waves / 128 pixels -- each wave owns 16 pixels
// (one MFMA B-set) -> 8 waves/SIMD (HW max). 4-tile global_load_lds
// intervals with inverse-swizzled source (rule #21) + verified conflict-free
// read swizzle. R1/R2/R4/R5/R6 falsified: reg-pipelining (collapses under
// VGPR pressure), barrier-count reduction (flat), fp16 margin (rescan
// blowup), in-kernel cnorm/convert fusion (uncoalesced per-thread row reads,
// +45 us). The ~60 us bench-vs-kernel gap is harness-fixed (persisted with a
// single kernel in R6), so the two-kernel split costs only ~10 us and keeps
// the main kernel minimal.
__global__ __launch_bounds__(512, 8) void vq_mfma_kernel(
        const float* __restrict__ z,
        const float* __restrict__ cb,
        const unsigned short* __restrict__ cb_hi,
        const unsigned short* __restrict__ cb_lo,
        const float* __restrict__ cnorm,
        float* __restrict__ zq,
        float* __restrict__ loss_out) {
    // [buf(2)][tile_in_interval(4)*256 + slot(256)] uint4 units, 32 KB.
    // Within one tile: slot = part*128 + row*8 + chunk^(row&7)  (R0 layout).
    __shared__ alignas(16) uint4  abuf[2][1024];
    __shared__ alignas(16) float  cn_lds[NK];   // 4 KB; rescan scratch aliases
    __shared__ int   finidx[PPB];
    __shared__ int   flags[PPB];
    __shared__ float redf[8];

    const int tid = threadIdx.x;
    const int g0  = blockIdx.x * PPB;
    const int bb  = g0 >> 12;
    const int pp0 = g0 & 4095;
    const float* zbase = z  + (size_t)bb * (NC * HW) + pp0;
    float*      zqbase = zq + (size_t)bb * (NC * HW) + pp0;

    // ---- stage cnorm -> LDS (512 threads x float2) ----
    ((float2*)cn_lds)[tid] = ((const float2*)cnorm)[tid];

    const int lane = tid & 63;
    const int w    = tid >> 6;        // wave 0..7 -> pixels w*16..w*16+15
    const int q    = lane >> 4;
    const int pcol = lane & 15;

    // ---- pre-swizzled global sources, 2 LDS slots per thread ----
    // Slot s (0..1023) = tt*256 + part*128 + row*8 + chunk. Thread tid fills
    // slots tid and tid+512 (linear dest = wave-uniform base + lane*16, as
    // global_load_lds requires). Slot chunk field c holds global chunk
    // c^(row&7)  -> XOR goes on the SOURCE (involution, rule #21).
    auto src_of = [&](int s) -> const char* {
        const int tt = s >> 8, part = (s >> 7) & 1;
        const int row = (s >> 3) & 15, chunk = s & 7;
        const char* bp = part ? (const char*)cb_lo : (const char*)cb_hi;
        return bp + tt * 2048 + row * 128 + ((chunk ^ (row & 7)) * 16);
    };
    const char* gsrc1 = src_of(tid);
    const char* gsrc2 = src_of(tid + 512);

    // one 4-tile interval of staging = 8 KB = 512 threads x 16B (x2 slots)
    auto stage_iv = [&](int iv, int buf) {
        __builtin_amdgcn_global_load_lds(
            (const __attribute__((address_space(1))) void*)
                (gsrc1 + (size_t)iv * 8192),
            (__attribute__((address_space(3))) void*)&abuf[buf][tid],
            16, 0, 0);
        __builtin_amdgcn_global_load_lds(
            (const __attribute__((address_space(1))) void*)
                (gsrc2 + (size_t)iv * 8192),
            (__attribute__((address_space(3))) void*)&abuf[buf][tid + 512],
            16, 0, 0);
    };

    stage_iv(0, 0);   // interval 0 in flight; z-loads below cover its latency

    // ---- B fragments straight from global: 16 strided floats per lane ----
    // B[k][n]: n = this wave's pixel (w*16+pcol), k = ks*32 + q*8 + t
    float zraw[2][8];
    #pragma unroll
    for (int ks = 0; ks < 2; ++ks)
        #pragma unroll
        for (int t = 0; t < 8; ++t)
            zraw[ks][t] = zbase[(size_t)(ks * 32 + q * 8 + t) * HW
                                + (w * 16 + pcol)];
    short8 Bh[2], Bl[2];
    #pragma unroll
    for (int ks = 0; ks < 2; ++ks)
        #pragma unroll
        for (int t = 0; t < 8; ++t) {
            float v = -2.0f * zraw[ks][t];
            unsigned short h = f2bf(v);
            unsigned short l = f2bf(v - bf2f(h));
            Bh[ks][t] = (short)h;
            Bl[ks][t] = (short)l;
        }

    // per-lane fixed read offsets (uint4 units within one tile's 256 slots)
    const int ridx0 = pcol * 8 + (q ^ (pcol & 7));        // chunk q  (k 0..31)
    const int ridx1 = pcol * 8 + ((4 + q) ^ (pcol & 7));  // chunk 4+q (k 32..63)

    __syncthreads();   // interval-0 staging drained (compiler vmcnt(0)) + cn_lds

    float B1 = FLT_MAX, B2 = FLT_MAX;
    int   I1 = 0;

    // ---- sweep 64 code tiles as 16 intervals of 4, double-buffered ----
    // Write-after-read safe: buf^1 was last read in interval iv-1, whose end
    // barrier precedes these stores.
    for (int iv = 0; iv < 16; ++iv) {
        if (iv < 15) stage_iv(iv + 1, (iv + 1) & 1);
        const short8* Abase = (const short8*)&abuf[iv & 1][0];
        #pragma unroll
        for (int tt = 0; tt < 4; ++tt) {
            const short8* A = Abase + tt * 256;
            short8 ah0 = A[ridx0];
            short8 ah1 = A[ridx1];
            short8 al0 = A[128 + ridx0];
            short8 al1 = A[128 + ridx1];
            const int tile = iv * 4 + tt;
            const floatx4 cn4 = *(const floatx4*)&cn_lds[tile * 16 + q * 4];
            const int kb = tile * 16 + q * 4;
            // score = cn + (-2z).e :  e_hi*z_hi + e_hi*z_lo + e_lo*z_hi
            floatx4 a0 = __builtin_amdgcn_mfma_f32_16x16x32_bf16(ah0, Bh[0], cn4, 0, 0, 0);
            floatx4 a1 = {0.f, 0.f, 0.f, 0.f};
            a1 = __builtin_amdgcn_mfma_f32_16x16x32_bf16(ah1, Bh[1], a1, 0, 0, 0);
            a0 = __builtin_amdgcn_mfma_f32_16x16x32_bf16(ah0, Bl[0], a0, 0, 0, 0);
            a1 = __builtin_amdgcn_mfma_f32_16x16x32_bf16(ah1, Bl[1], a1, 0, 0, 0);
            a0 = __builtin_amdgcn_mfma_f32_16x16x32_bf16(al0, Bh[0], a0, 0, 0, 0);
            a1 = __builtin_amdgcn_mfma_f32_16x16x32_bf16(al1, Bh[1], a1, 0, 0, 0);

            // C/D layout: code row = q*4+reg, pixel col = lane&15 (verified)
            #pragma unroll
            for (int i = 0; i < 4; ++i) {
                float s = a0[i] + a1[i];
                bool lt = s < B1;                    // strict: first min wins
                I1 = lt ? (kb + i) : I1;
                B2 = __builtin_amdgcn_fmed3f(s, B1, B2);
                B1 = fminf(s, B1);
            }
        }
        __syncthreads();
    }

    // ---- merge top-2 across the 4 lanes sharing each pixel (xor 16,32) ----
    {
        float b1 = B1, b2 = B2;
        int i1 = I1;
        #pragma unroll
        for (int d = 16; d <= 32; d <<= 1) {
            float ob1 = __shfl_xor(b1, d);
            float ob2 = __shfl_xor(b2, d);
            int   oi1 = __shfl_xor(i1, d);
            // second-smallest of {b1,b2,ob1,ob2}; equal b1s -> gap 0 -> rescan
            float nb2 = fminf(fmaxf(b1, ob1), fminf(b2, ob2));
            bool lt = (ob1 < b1) || (ob1 == b1 && oi1 < i1);
            b1 = lt ? ob1 : b1;
            i1 = lt ? oi1 : i1;
            b2 = nb2;
        }
        if (q == 0) {
            const int px = w * 16 + pcol;
            finidx[px] = i1;
            flags[px]  = (b2 - b1 < MARGIN) ? 1 : 0;
        }
    }
    int myflag = 0;
    __syncthreads();
    if (tid < PPB) myflag = flags[tid];
    const int nflag = __syncthreads_count(myflag);

    // ---- rare cooperative exact fp64 rescan ----
    // red_s aliases cn_lds (512 doubles = 4 KB); red_i aliases abuf (free).
    if (nflag > 0) {
        double* red_s = reinterpret_cast<double*>(cn_lds);
        int*    red_i = reinterpret_cast<int*>(&abuf[0][0]);
        for (int p = 0; p < PPB; ++p) {
            if (flags[p]) {
                const float* zp = zbase + p;
                double bd = 1.0e300; int bi = 0;
                #pragma unroll 1
                for (int r = 0; r < 2; ++r) {
                    const int k = tid * 2 + r;
                    const float* rowp = cb + (size_t)k * NC;
                    double s = 0.0;
                    for (int c = 0; c < NC; ++c) {
                        double t = (double)zp[(size_t)c * HW] - (double)rowp[c];
                        s = fma(t, t, s);
                    }
                    if (s < bd) { bd = s; bi = k; }  // k increasing: first min
                }
                red_s[tid] = bd; red_i[tid] = bi;
                __syncthreads();
                if (tid < 64) {
                    double m = red_s[tid]; int mi = red_i[tid];
                    #pragma unroll
                    for (int t = 1; t < 8; ++t) {
                        double om = red_s[tid + 64 * t];
                        int    oi = red_i[tid + 64 * t];
                        if (om < m || (om == m && oi < mi)) { m = om; mi = oi; }
                    }
                    #pragma unroll
                    for (int off = 32; off > 0; off >>= 1) {
                        double om = __shfl_down(m, off);
                        int    oi = __shfl_down(mi, off);
                        if (om < m || (om == m && oi < mi)) { m = om; mi = oi; }
                    }
                    if (tid == 0) finidx[p] = mi;
                }
                __syncthreads();
            }
        }
        __syncthreads();
    }

    // ---- epilogue: gather exact fp32 code row -> z_q, loss SSE ----
    // 4 threads per pixel, 16 channels each.
    {
        const int p  = tid & (PPB - 1);
        const int qq = tid >> 7;             // 0..3
        const int fi = finidx[p];
        const float4* crow4 = (const float4*)(cb + (size_t)fi * NC) + qq * 4;
        float sse = 0.f;
        #pragma unroll
        for (int j = 0; j < 4; ++j) {
            const float4 qv = crow4[j];
            const size_t c0 = (size_t)(qq * 16 + 4 * j) * HW + p;
            const float z0 = zbase[c0];
            const float z1 = zbase[c0 + HW];
            const float z2 = zbase[c0 + 2 * (size_t)HW];
            const float z3 = zbase[c0 + 3 * (size_t)HW];
            zqbase[c0]                  = qv.x;   // coalesced across threads
            zqbase[c0 + HW]             = qv.y;
            zqbase[c0 + 2 * (size_t)HW] = qv.z;
            zqbase[c0 + 3 * (size_t)HW] = qv.w;
            float t0 = qv.x - z0, t1 = qv.y - z1, t2 = qv.z - z2, t3 = qv.w - z3;
            sse = fmaf(t0, t0, sse);
            sse = fmaf(t1, t1, sse);
            sse = fmaf(t2, t2, sse);
            sse = fmaf(t3, t3, sse);
        }
        #pragma unroll
        for (int off = 32; off > 0; off >>= 1) sse += __shfl_down(sse, off);
        if ((tid & 63) == 0) redf[tid >> 6] = sse;
        __syncthreads();
        if (tid == 0) {
            float tot = 0.f;
            #pragma unroll
            for (int r = 0; r < 8; ++r) tot += redf[r];
            atomicAdd(loss_out, tot * (1.25f / (float)TOTAL));
        }
    }
}

extern "C" void kernel_launch(void* const* d_in, const int* in_sizes, int n_in,
                              void* d_out, int out_size, void* d_ws, size_t ws_size,
                              hipStream_t stream) {
    const float* z  = (const float*)d_in[0];   // [32, 64, 64, 64] fp32
    const float* cb = (const float*)d_in[1];   // [1024, 64] fp32
    float* out      = (float*)d_out;           // z_q ++ loss
    float* zqp      = out;
    float* loss     = out + TOTAL;

    // ws: cnorm fp32[1024] | cb_hi bf16[1024*64] | cb_lo bf16[1024*64]
    float* cnorm          = (float*)d_ws;
    unsigned short* cb_hi = (unsigned short*)((char*)d_ws + 4096);
    unsigned short* cb_lo = (unsigned short*)((char*)d_ws + 4096 + NK * NC * 2);

    vq_prep_kernel<<<68, 256, 0, stream>>>(cb, cnorm, cb_hi, cb_lo, loss);
    vq_mfma_kernel<<<NPIX / PPB, 512, 0, stream>>>(z, cb, cb_hi, cb_lo, cnorm,
                                                   zqp, loss);
}